// Round 1
// baseline (470483.154 us; speedup 1.0000x reference)
//
#include <hip/hip_runtime.h>
#include <math.h>

// ControlledNODE: sequential RK4 scan, T=65536 steps.
// One persistent block (128 threads = 2 waves on one CU).
// Thread j owns hidden unit j: W1/W2 columns + a W3 slice live in VGPRs
// for the whole kernel. Activations broadcast through LDS.

constexpr int T_STEPS = 65536;
constexpr int HD  = 32;   // state dim
constexpr int UD  = 8;    // control dim
constexpr int HID = 128;  // hidden dim

__device__ __forceinline__ float silu_f(float a) {
    // a * sigmoid(a) = a / (1 + exp(-a)); exp overflow -> inf -> result 0 (correct limit)
    return a / (1.0f + __expf(-a));
}

__global__ __launch_bounds__(128, 1)
void node_scan(const float* __restrict__ U,
               const float* __restrict__ h0,
               const float* __restrict__ W1, const float* __restrict__ b1,
               const float* __restrict__ W2, const float* __restrict__ b2,
               const float* __restrict__ W3, const float* __restrict__ b3,
               const float* __restrict__ Wd, const float* __restrict__ bd,
               const float* __restrict__ Wt, const float* __restrict__ bt,
               const float* __restrict__ Wc, const float* __restrict__ bc,
               float* __restrict__ out)
{
    const int tid = threadIdx.x;
    const int j   = tid;        // hidden unit 0..127
    const int m   = tid & 31;   // drift output index (L3)
    const int seg = tid >> 5;   // L3 K-segment 0..3 (also head group 0..2)

    __shared__ __align__(16) float xbuf[HD];    // current RK-stage state input (32)
    __shared__ __align__(16) float z1buf[HID];
    __shared__ __align__(16) float z2buf[HID];
    __shared__ __align__(16) float pbuf[HID];   // L3 partials
    __shared__ __align__(16) float hbuf[HD];    // persistent h_t

    // ---- one-time: weights into registers ----
    float w1r[40];
#pragma unroll
    for (int i = 0; i < 40; ++i) w1r[i] = W1[i * HID + j];
    const float b1r = b1[j];

    float w2r[HID];
#pragma unroll
    for (int i = 0; i < HID; ++i) w2r[i] = W2[i * HID + j];
    const float b2r = b2[j];

    float w3r[32];
#pragma unroll
    for (int i = 0; i < 32; ++i) w3r[i] = W3[(seg * 32 + i) * HD + m];
    const float b3r = (tid < HD) ? b3[m] : 0.0f;

    // heads: threads 0..95, group g = seg (0=d,1=t,2=c), element i = m
    float whr = 0.0f, bhr = 0.0f;
    if (seg == 0)      { whr = Wd[m]; bhr = bd[0]; }
    else if (seg == 1) { whr = Wt[m]; bhr = bt[0]; }
    else if (seg == 2) { whr = Wc[m]; bhr = bc[0]; }

    if (tid < HD) { float h = h0[tid]; hbuf[tid] = h; xbuf[tid] = h; }

    const float DT  = 5.0f / 60.0f;
    const float HDT = 0.5f * DT;
    const float W6  = DT / 6.0f;

    float kacc = 0.0f;  // lanes 0..31: k1 + 2k2 + 2k3 + k4

    // u double-buffer in registers (broadcast loads, L2-cached)
    float4 ua = *(const float4*)(U);
    float4 ub = *(const float4*)(U + 4);

    __syncthreads();

    for (int t = 0; t < T_STEPS; ++t) {
        // prefetch next step's u
        const int tn = (t + 1 < T_STEPS) ? (t + 1) : t;
        const float4 na = *(const float4*)(U + tn * 8);
        const float4 nb = *(const float4*)(U + tn * 8 + 4);

        // ---- heads from current h (before update) ----
        {
            float p = (tid < 96) ? hbuf[m] * whr : 0.0f;
            p += __shfl_xor(p, 16);
            p += __shfl_xor(p, 8);
            p += __shfl_xor(p, 4);
            p += __shfl_xor(p, 2);
            p += __shfl_xor(p, 1);
            if (tid < 96 && m == 0) out[seg * T_STEPS + t] = p + bhr;
        }

        const float us[8] = {ua.x, ua.y, ua.z, ua.w, ub.x, ub.y, ub.z, ub.w};

#pragma unroll
        for (int st = 0; st < 4; ++st) {
            // ---- L1: z1 = silu([x,u] @ W1 + b1) ----
            float a0 = b1r, a1 = 0.0f, a2 = 0.0f, a3 = 0.0f;
            const float4* xb4 = (const float4*)xbuf;
#pragma unroll
            for (int i4 = 0; i4 < 8; ++i4) {
                const float4 v = xb4[i4];
                a0 += v.x * w1r[4 * i4 + 0];
                a1 += v.y * w1r[4 * i4 + 1];
                a2 += v.z * w1r[4 * i4 + 2];
                a3 += v.w * w1r[4 * i4 + 3];
            }
#pragma unroll
            for (int i = 0; i < 8; ++i) a0 += us[i] * w1r[32 + i];
            z1buf[j] = silu_f((a0 + a1) + (a2 + a3));
            __syncthreads();

            // ---- L2: z2 = silu(z1 @ W2 + b2) ----
            a0 = b2r; a1 = 0.0f; a2 = 0.0f; a3 = 0.0f;
            const float4* zb4 = (const float4*)z1buf;
#pragma unroll
            for (int i4 = 0; i4 < 32; ++i4) {
                const float4 v = zb4[i4];
                a0 += v.x * w2r[4 * i4 + 0];
                a1 += v.y * w2r[4 * i4 + 1];
                a2 += v.z * w2r[4 * i4 + 2];
                a3 += v.w * w2r[4 * i4 + 3];
            }
            z2buf[j] = silu_f((a0 + a1) + (a2 + a3));
            __syncthreads();

            // ---- L3 partial: drift_m partial over segment seg ----
            a0 = 0.0f; a1 = 0.0f; a2 = 0.0f; a3 = 0.0f;
            const float4* z2s = (const float4*)(z2buf + seg * 32);
#pragma unroll
            for (int i4 = 0; i4 < 8; ++i4) {
                const float4 v = z2s[i4];
                a0 += v.x * w3r[4 * i4 + 0];
                a1 += v.y * w3r[4 * i4 + 1];
                a2 += v.z * w3r[4 * i4 + 2];
                a3 += v.w * w3r[4 * i4 + 3];
            }
            pbuf[tid] = (a0 + a1) + (a2 + a3);
            __syncthreads();

            // ---- combine: k-stage update (lanes 0..31) ----
            if (tid < HD) {
                const float drift = ((pbuf[m] + pbuf[m + 32]) + (pbuf[m + 64] + pbuf[m + 96])) + b3r;
                const float s = xbuf[m];                 // this stage's input state
                const float k = 0.02f * drift - 0.1f * s;
                if (st == 0) {
                    kacc = k;
                    xbuf[m] = hbuf[m] + HDT * k;
                } else if (st == 1) {
                    kacc += 2.0f * k;
                    xbuf[m] = hbuf[m] + HDT * k;
                } else if (st == 2) {
                    kacc += 2.0f * k;
                    xbuf[m] = hbuf[m] + DT * k;
                } else {
                    kacc += k;
                    float hn = hbuf[m] + W6 * kacc;
                    if (!isfinite(hn)) hn = 0.0f;        // nan_to_num BEFORE tanh
                    hn = tanhf(hn);
                    hn = fminf(fmaxf(hn, -5.0f), 5.0f);  // clip (no-op after tanh, kept for fidelity)
                    hbuf[m] = hn;
                    xbuf[m] = hn;
                }
            }
            __syncthreads();
        }
        ua = na; ub = nb;
    }

    if (tid < HD) out[3 * T_STEPS + tid] = hbuf[tid];
}

extern "C" void kernel_launch(void* const* d_in, const int* in_sizes, int n_in,
                              void* d_out, int out_size, void* d_ws, size_t ws_size,
                              hipStream_t stream) {
    const float* U  = (const float*)d_in[0];
    const float* h0 = (const float*)d_in[1];
    const float* W1 = (const float*)d_in[2];
    const float* b1 = (const float*)d_in[3];
    const float* W2 = (const float*)d_in[4];
    const float* b2 = (const float*)d_in[5];
    const float* W3 = (const float*)d_in[6];
    const float* b3 = (const float*)d_in[7];
    const float* Wd = (const float*)d_in[8];
    const float* bd = (const float*)d_in[9];
    const float* Wt = (const float*)d_in[10];
    const float* bt = (const float*)d_in[11];
    const float* Wc = (const float*)d_in[12];
    const float* bc = (const float*)d_in[13];
    float* out = (float*)d_out;

    node_scan<<<1, 128, 0, stream>>>(U, h0, W1, b1, W2, b2, W3, b3,
                                     Wd, bd, Wt, bt, Wc, bc, out);
}